// Round 6
// baseline (172.995 us; speedup 1.0000x reference)
//
#include <hip/hip_runtime.h>
#include <hip/hip_bf16.h>

// MoE MLP: x[1,2048,768] fp32, router_w[16,768], w1[768,12288], w2[12288,768]
// out[1,2048,768] fp32.  Experts: 8x512 + 8x1024, top-8, normalized.
// Dense bf16 GEMMs (reference is dense+masked); comb folded into H.
// GEMM core: 256x256 tile, BK=32, QUAD-buffered LDS (stage 2 tiles ahead),
// 32x32x16 MFMA (half the instrs/FLOP), 1 raw barrier + counted vmcnt(4)
// per tile, XOR-swizzled LDS, setprio, XCD-ownership block mapping.

#define T_TOK 2048
#define D_EMB 768
#define W_TOT 12288
#define N_EXP 16

typedef __attribute__((ext_vector_type(16))) float f32x16;
typedef __attribute__((ext_vector_type(8))) short bf16x8;

typedef __attribute__((address_space(1))) const unsigned int as1c_u32;
typedef __attribute__((address_space(3))) unsigned int as3_u32;

__device__ __forceinline__ void gload16(const void* g, void* l) {
  __builtin_amdgcn_global_load_lds((as1c_u32*)g, (as3_u32*)l, 16, 0, 0);
}

__device__ __forceinline__ unsigned short f2bf(float f) {
  __hip_bfloat16 h = __float2bfloat16(f);
  return *reinterpret_cast<unsigned short*>(&h);
}

__device__ __forceinline__ float gelu_f(float x) {
  // jax.nn.gelu default (approximate=True, tanh form)
  float x3 = x * x * x;
  float a = 0.7978845608028654f * __builtin_fmaf(0.044715f, x3, x);
  a = fminf(fmaxf(a, -20.f), 20.f);
  float e = __expf(-2.0f * a);
  float t = (1.0f - e) / (1.0f + e);
  return 0.5f * x * (1.0f + t);
}

// in fp32 [R][C] -> out bf16 [C][R]
__global__ __launch_bounds__(256) void transpose_cvt_kernel(
    const float* __restrict__ in, unsigned short* __restrict__ out, int R, int C) {
  __shared__ float tile[32][33];
  int c0 = blockIdx.x * 32;
  int r0 = blockIdx.y * 32;
  int i = threadIdx.x;
  {
    int r = i >> 3, c4 = (i & 7) * 4;
    float4 v = *(const float4*)(in + (size_t)(r0 + r) * C + c0 + c4);
    tile[r][c4 + 0] = v.x; tile[r][c4 + 1] = v.y;
    tile[r][c4 + 2] = v.z; tile[r][c4 + 3] = v.w;
  }
  __syncthreads();
  {
    int c = i >> 3, r4 = (i & 7) * 4;
    ushort4 o;
    o.x = f2bf(tile[r4 + 0][c]);
    o.y = f2bf(tile[r4 + 1][c]);
    o.z = f2bf(tile[r4 + 2][c]);
    o.w = f2bf(tile[r4 + 3][c]);
    *(ushort4*)(out + (size_t)(c0 + c) * R + r0 + r4) = o;
  }
}

// ---------------- router (also emits xb = bf16(x)) ----------------

__global__ __launch_bounds__(256) void router_kernel(
    const float* __restrict__ x, const float* __restrict__ rw,
    float* __restrict__ comb, unsigned short* __restrict__ xbout) {
  int tid = threadIdx.x, lane = tid & 63, w = tid >> 6;
  int t = blockIdx.x * 4 + w;
  const float* xr = x + (size_t)t * D_EMB;
  float xv[12];
#pragma unroll
  for (int i = 0; i < 12; ++i) xv[i] = xr[lane + 64 * i];
#pragma unroll
  for (int i = 0; i < 12; ++i)
    xbout[(size_t)t * D_EMB + lane + 64 * i] = f2bf(xv[i]);
  float lg[16];
#pragma unroll
  for (int e = 0; e < 16; ++e) {
    const float* we = rw + (size_t)e * D_EMB;
    float p = 0.f;
#pragma unroll
    for (int i = 0; i < 12; ++i) p = __builtin_fmaf(xv[i], we[lane + 64 * i], p);
#pragma unroll
    for (int off = 32; off >= 1; off >>= 1) p += __shfl_xor(p, off, 64);
    lg[e] = p;
  }
  float mx = lg[0];
#pragma unroll
  for (int e = 1; e < 16; ++e) mx = fmaxf(mx, lg[e]);
  float ex[16];
#pragma unroll
  for (int e = 0; e < 16; ++e) ex[e] = __expf(lg[e] - mx);
  float selsum = 0.f, myval = 0.f;
#pragma unroll
  for (int e = 0; e < 16; ++e) {
    int rank = 0;
#pragma unroll
    for (int e2 = 0; e2 < 16; ++e2)
      rank += (ex[e2] > ex[e]) || (ex[e2] == ex[e] && e2 < e);
    bool sel = rank < 8;
    float v = sel ? ex[e] : 0.f;
    selsum += v;
    if (e == lane) myval = v;
  }
  if (lane < 16) comb[(size_t)t * N_EXP + lane] = myval / selsum;
}

// ------ 8-wave quad-buffered GEMM, 256x256 tile, BK=32, 32x32x16 MFMA ------
// A row-major [M][lda], B N-major [N][ldb] (bf16, K contiguous).
// 8 waves = 2(M) x 4(N); per-wave 128x64 output = 4m x 2n of 32x32.
// Per tile: 4 staging loads (tile t+2 -> buf[(t+2)&3]); per-wave vmcnt(4)
// then s_barrier at tile top guarantees tile t fully in LDS and makes
// overwriting buf[(t+2)&3] (last read at t-2) safe.
// LDS rows are 64B; swizzle: 16B-slot ^= (row>>1)&3 (2-pass min per group).
// MAP: 0 = gemm1 (grid 384, XCD owns 6 N-panels), 1 = gemm2 (grid 192,
// XCD = K-split). EPI: 1 = gelu*comb -> bf16 H, 0 = fp32 partial.

template <int EPI, int MAP>
__global__ __launch_bounds__(512, 2) void gemm_kernel(
    const unsigned short* __restrict__ Ag, const unsigned short* __restrict__ Bg,
    int lda, int ldb, int ntiles, int kchunk,
    const float* __restrict__ comb, unsigned short* __restrict__ hout,
    float* __restrict__ pout) {
  __shared__ __align__(16) char smem[131072];  // A 4x16KB | B 4x16KB

  const int tid = threadIdx.x;
  const int lane = tid & 63;
  const int wid = tid >> 6;
  const int wr = wid >> 2;        // 0..1  (M half: 128 rows)
  const int wc = wid & 3;         // 0..3  (N quarter: 64 cols)

  int mt, nt, zt;
  {
    int bid = blockIdx.x;
    if (MAP == 0) {               // gemm1: xcd owns 6 N-panels, M fastest
      int xcd = bid & 7, r = bid >> 3;        // r in 0..47
      nt = xcd * 6 + (r >> 3); mt = r & 7; zt = 0;
    } else {                      // gemm2: xcd = K-split
      zt = bid & 7; int r = bid >> 3;         // r in 0..23
      nt = r % 3; mt = r / 3;
    }
  }
  const int rm0 = mt * 256;
  const int cn0 = nt * 256;
  const int kbeg = zt * kchunk;

  // ---- staging: pre-swizzled global source, linear LDS dest (rule #21) ----
  auto stageA = [&](int b, int j, int kt) {
    int off = j * 8192 + tid * 16;
    int row = off >> 6;                       // 0..255
    int scol = (((off >> 4) & 3) ^ ((row >> 1) & 3)) << 4;
    const char* src = (const char*)Ag +
        ((size_t)(rm0 + row) * lda + (kbeg + kt * 32)) * 2 + scol;
    gload16(src, smem + b * 16384 + j * 8192 + wid * 1024);
  };
  auto stageB = [&](int b, int j, int kt) {
    int off = j * 8192 + tid * 16;
    int row = off >> 6;
    int scol = (((off >> 4) & 3) ^ ((row >> 1) & 3)) << 4;
    const char* src = (const char*)Bg +
        ((size_t)(cn0 + row) * ldb + (kbeg + kt * 32)) * 2 + scol;
    gload16(src, smem + 65536 + b * 16384 + j * 8192 + wid * 1024);
  };
  auto rdA = [&](int b, int m, int ks) {
    int row = wr * 128 + m * 32 + (lane & 31);
    int col = (ks * 32 + ((lane >> 5) << 4)) ^ (((row >> 1) & 3) << 4);
    return *(const bf16x8*)(smem + b * 16384 + row * 64 + col);
  };
  auto rdB = [&](int b, int n, int ks) {
    int row = wc * 64 + n * 32 + (lane & 31);
    int col = (ks * 32 + ((lane >> 5) << 4)) ^ (((row >> 1) & 3) << 4);
    return *(const bf16x8*)(smem + 65536 + b * 16384 + row * 64 + col);
  };

  f32x16 acc[4][2];
#pragma unroll
  for (int m = 0; m < 4; ++m)
#pragma unroll
    for (int n = 0; n < 2; ++n)
#pragma unroll
      for (int r = 0; r < 16; ++r) acc[m][n][r] = 0.f;

  // prologue: stage tiles 0,1 into bufs 0,1 (4 loads each, per wave)
  stageA(0, 0, 0); stageA(0, 1, 0); stageB(0, 0, 0); stageB(0, 1, 0);
  stageA(1, 0, 1); stageA(1, 1, 1); stageB(1, 0, 1); stageB(1, 1, 1);
  __builtin_amdgcn_sched_barrier(0);

#pragma unroll 4
  for (int t = 0; t < ntiles; ++t) {
    const int b = t & 3;
    const int nb = (t + 2) & 3;
    const int kt2 = (t + 2 < ntiles) ? t + 2 : ntiles - 1;  // clamp tail

    // gate: own slice of tile t landed; barrier makes it collective and
    // licenses overwrite of buf[(t+2)&3] (last read at tile t-2).
    asm volatile("s_waitcnt vmcnt(4)" ::: "memory");
    __builtin_amdgcn_s_barrier();
    __builtin_amdgcn_sched_barrier(0);

    bf16x8 af[4][2], bf[2][2];
#pragma unroll
    for (int m = 0; m < 4; ++m)
#pragma unroll
      for (int ks = 0; ks < 2; ++ks) af[m][ks] = rdA(b, m, ks);
#pragma unroll
    for (int n = 0; n < 2; ++n)
#pragma unroll
      for (int ks = 0; ks < 2; ++ks) bf[n][ks] = rdB(b, n, ks);

    stageA(nb, 0, kt2); stageA(nb, 1, kt2);
    stageB(nb, 0, kt2); stageB(nb, 1, kt2);
    __builtin_amdgcn_sched_barrier(0);

    __builtin_amdgcn_s_setprio(1);
#pragma unroll
    for (int m = 0; m < 4; ++m)
#pragma unroll
      for (int n = 0; n < 2; ++n)
#pragma unroll
        for (int ks = 0; ks < 2; ++ks)
          acc[m][n] = __builtin_amdgcn_mfma_f32_32x32x16_bf16(
              af[m][ks], bf[n][ks], acc[m][n], 0, 0, 0);
    __builtin_amdgcn_s_setprio(0);
  }

  asm volatile("s_waitcnt vmcnt(0)" ::: "memory");  // drain tail stages
  __syncthreads();

  // ---- epilogue ----
  // C/D 32x32: col = lane&31, row = (r&3) + 8*(r>>2) + 4*(lane>>5)
  const int rbase = wr * 128 + 4 * (lane >> 5);
  if constexpr (EPI == 1) {
    float* Cwf = (float*)smem;   // reuse staging LDS: [256 rows][16 experts]
    {
      int row = tid >> 1, c8 = (tid & 1) * 8;
      const float* s = comb + (size_t)(rm0 + row) * N_EXP + c8;
      *(float4*)&Cwf[row * 16 + c8] = *(const float4*)s;
      *(float4*)&Cwf[row * 16 + c8 + 4] = *(const float4*)(s + 4);
    }
    __syncthreads();
#pragma unroll
    for (int n = 0; n < 2; ++n) {
      int colg0 = cn0 + wc * 64 + n * 32;
      int e = (colg0 < 4096) ? (colg0 >> 9) : (8 + ((colg0 - 4096) >> 10));
      int col = colg0 + (lane & 31);
#pragma unroll
      for (int m = 0; m < 4; ++m) {
#pragma unroll
        for (int r = 0; r < 16; ++r) {
          int rl = rbase + m * 32 + (r & 3) + 8 * (r >> 2);
          float v = gelu_f(acc[m][n][r]) * Cwf[rl * 16 + e];
          hout[(size_t)(rm0 + rl) * W_TOT + col] = f2bf(v);
        }
      }
    }
  } else {
    float* pz = pout + (size_t)zt * T_TOK * D_EMB;
#pragma unroll
    for (int n = 0; n < 2; ++n) {
      int col = cn0 + wc * 64 + n * 32 + (lane & 31);
#pragma unroll
      for (int m = 0; m < 4; ++m) {
#pragma unroll
        for (int r = 0; r < 16; ++r) {
          int rl = rbase + m * 32 + (r & 3) + 8 * (r >> 2);
          pz[(size_t)(rm0 + rl) * D_EMB + col] = acc[m][n][r];
        }
      }
    }
  }
}

__global__ __launch_bounds__(256) void reduce_kernel(
    const float* __restrict__ partial, float* __restrict__ out, int splits) {
  int i = (blockIdx.x * 256 + threadIdx.x) * 4;
  if (i >= T_TOK * D_EMB) return;
  float4 s = *(const float4*)(partial + i);
  for (int sp = 1; sp < splits; ++sp) {
    float4 v = *(const float4*)(partial + (size_t)sp * T_TOK * D_EMB + i);
    s.x += v.x; s.y += v.y; s.z += v.z; s.w += v.w;
  }
  *(float4*)(out + i) = s;
}

// ---------------- launcher ----------------

extern "C" void kernel_launch(void* const* d_in, const int* in_sizes, int n_in,
                              void* d_out, int out_size, void* d_ws, size_t ws_size,
                              hipStream_t stream) {
  const float* x = (const float*)d_in[0];
  const float* router_w = (const float*)d_in[1];
  const float* w1 = (const float*)d_in[2];
  const float* w2 = (const float*)d_in[3];
  float* out = (float*)d_out;

  char* ws = (char*)d_ws;
  size_t off = 0;
  auto alloc = [&](size_t bytes) {
    char* p = ws + off;
    off += (bytes + 255) & ~(size_t)255;
    return p;
  };
  unsigned short* xb  = (unsigned short*)alloc((size_t)T_TOK * D_EMB * 2);
  unsigned short* w1t = (unsigned short*)alloc((size_t)W_TOT * D_EMB * 2);
  unsigned short* w2t = (unsigned short*)alloc((size_t)D_EMB * W_TOT * 2);
  unsigned short* h   = (unsigned short*)alloc((size_t)T_TOK * W_TOT * 2);
  float* comb         = (float*)alloc((size_t)T_TOK * N_EXP * 4);

  const int splits = 8;                     // 192 blocks; ntiles=48 (div 4)
  float* partial = (float*)alloc((size_t)splits * T_TOK * D_EMB * 4);
  int kchunk = W_TOT / splits;

  transpose_cvt_kernel<<<dim3(W_TOT / 32, D_EMB / 32), 256, 0, stream>>>(w1, w1t, D_EMB, W_TOT);
  transpose_cvt_kernel<<<dim3(D_EMB / 32, W_TOT / 32), 256, 0, stream>>>(w2, w2t, W_TOT, D_EMB);
  router_kernel<<<T_TOK / 4, 256, 0, stream>>>(x, router_w, comb, xb);

  // GEMM1: H = gelu(X W1) * comb ; grid 384 = 8 XCD x (6 N x 8 M)
  gemm_kernel<1, 0><<<384, 512, 0, stream>>>(
      xb, w1t, D_EMB, D_EMB, D_EMB / 32, D_EMB, comb, h, nullptr);

  // GEMM2: OUT = H W2 ; grid 192 = 8 splits x (3 N x 8 M)
  gemm_kernel<0, 1><<<192, 512, 0, stream>>>(
      h, w2t, W_TOT, W_TOT, kchunk / 32, kchunk, nullptr, nullptr, partial);

  reduce_kernel<<<(T_TOK * D_EMB) / 1024, 256, 0, stream>>>(partial, out, splits);
}

// Round 8
// 136.934 us; speedup vs baseline: 1.2633x; 1.2633x over previous
//
#include <hip/hip_runtime.h>
#include <hip/hip_bf16.h>

// MoE MLP: x[1,2048,768] fp32, router_w[16,768], w1[768,12288], w2[12288,768]
// out[1,2048,768] fp32.  Experts: 8x512 + 8x1024, top-8, normalized.
// Dense bf16 GEMMs (reference is dense+masked); comb folded into H.
// GEMM core: R5-proven schedule (256x192 tile, BK=64, 8 waves 2Mx4N, dbuf,
// 2-phase/K-tile COUNTED vmcnt, XOR-swizzled LDS, setprio, XCD mapping) +
// affine addressing: 7 loop-carried global pointers advanced +128B/tile
// (builtin offset always 0), unconditional tail stage (one-past-end tile is
// in-bounds of adjacent ws buffers and never read), precomputed LDS read
// bases + runtime buffer-toggle so ds_read offsets are immediates.

#define T_TOK 2048
#define D_EMB 768
#define W_TOT 12288
#define N_EXP 16

typedef __attribute__((ext_vector_type(4))) float f32x4;
typedef __attribute__((ext_vector_type(8))) short bf16x8;

typedef __attribute__((address_space(1))) const unsigned int as1c_u32;
typedef __attribute__((address_space(3))) unsigned int as3_u32;

__device__ __forceinline__ void gload16(const void* g, void* l) {
  __builtin_amdgcn_global_load_lds((as1c_u32*)g, (as3_u32*)l, 16, 0, 0);
}

__device__ __forceinline__ unsigned short f2bf(float f) {
  __hip_bfloat16 h = __float2bfloat16(f);
  return *reinterpret_cast<unsigned short*>(&h);
}

__device__ __forceinline__ float gelu_f(float x) {
  // jax.nn.gelu default (approximate=True, tanh form)
  float x3 = x * x * x;
  float a = 0.7978845608028654f * __builtin_fmaf(0.044715f, x3, x);
  a = fminf(fmaxf(a, -20.f), 20.f);
  float e = __expf(-2.0f * a);
  float t = (1.0f - e) / (1.0f + e);
  return 0.5f * x * (1.0f + t);
}

// in fp32 [R][C] -> out bf16 [C][R]
__global__ __launch_bounds__(256) void transpose_cvt_kernel(
    const float* __restrict__ in, unsigned short* __restrict__ out, int R, int C) {
  __shared__ float tile[32][33];
  int c0 = blockIdx.x * 32;
  int r0 = blockIdx.y * 32;
  int i = threadIdx.x;
  {
    int r = i >> 3, c4 = (i & 7) * 4;
    float4 v = *(const float4*)(in + (size_t)(r0 + r) * C + c0 + c4);
    tile[r][c4 + 0] = v.x; tile[r][c4 + 1] = v.y;
    tile[r][c4 + 2] = v.z; tile[r][c4 + 3] = v.w;
  }
  __syncthreads();
  {
    int c = i >> 3, r4 = (i & 7) * 4;
    ushort4 o;
    o.x = f2bf(tile[r4 + 0][c]);
    o.y = f2bf(tile[r4 + 1][c]);
    o.z = f2bf(tile[r4 + 2][c]);
    o.w = f2bf(tile[r4 + 3][c]);
    *(ushort4*)(out + (size_t)(c0 + c) * R + r0 + r4) = o;
  }
}

// ---------------- router (also emits xb = bf16(x)) ----------------

__global__ __launch_bounds__(256) void router_kernel(
    const float* __restrict__ x, const float* __restrict__ rw,
    float* __restrict__ comb, unsigned short* __restrict__ xbout) {
  int tid = threadIdx.x, lane = tid & 63, w = tid >> 6;
  int t = blockIdx.x * 4 + w;
  const float* xr = x + (size_t)t * D_EMB;
  float xv[12];
#pragma unroll
  for (int i = 0; i < 12; ++i) xv[i] = xr[lane + 64 * i];
#pragma unroll
  for (int i = 0; i < 12; ++i)
    xbout[(size_t)t * D_EMB + lane + 64 * i] = f2bf(xv[i]);
  float lg[16];
#pragma unroll
  for (int e = 0; e < 16; ++e) {
    const float* we = rw + (size_t)e * D_EMB;
    float p = 0.f;
#pragma unroll
    for (int i = 0; i < 12; ++i) p = __builtin_fmaf(xv[i], we[lane + 64 * i], p);
#pragma unroll
    for (int off = 32; off >= 1; off >>= 1) p += __shfl_xor(p, off, 64);
    lg[e] = p;
  }
  float mx = lg[0];
#pragma unroll
  for (int e = 1; e < 16; ++e) mx = fmaxf(mx, lg[e]);
  float ex[16];
#pragma unroll
  for (int e = 0; e < 16; ++e) ex[e] = __expf(lg[e] - mx);
  float selsum = 0.f, myval = 0.f;
#pragma unroll
  for (int e = 0; e < 16; ++e) {
    int rank = 0;
#pragma unroll
    for (int e2 = 0; e2 < 16; ++e2)
      rank += (ex[e2] > ex[e]) || (ex[e2] == ex[e] && e2 < e);
    bool sel = rank < 8;
    float v = sel ? ex[e] : 0.f;
    selsum += v;
    if (e == lane) myval = v;
  }
  if (lane < 16) comb[(size_t)t * N_EXP + lane] = myval / selsum;
}

// ------------- 8-wave counted-vmcnt pipelined GEMM, 256x192 -------------
// Per K-tile: 7 loads in order [B0,B1,B2,A0,A2 | A1,A3]; phase0 waits
// vmcnt(2) (B*,A0,A2 of cur landed), phase1 waits vmcnt(5) (A1,A3 landed).
// Loads issued in tile t are consumed in tile t+1 (never drain to 0).
// MAP: 0 = gemm1 XCD-owns-N (grid 512), 1 = gemm2 XCD=zt (grid 256).
// EPI: 1 = gelu*comb -> bf16 H, 0 = fp32 partial.

template <int EPI, int MAP>
__global__ __launch_bounds__(512, 2) void gemm_kernel(
    const unsigned short* __restrict__ Ag, const unsigned short* __restrict__ Bg,
    int lda, int ldb, int ntiles, int kchunk,
    const float* __restrict__ comb, unsigned short* __restrict__ hout,
    float* __restrict__ pout) {
  __shared__ __align__(16) char smem[114688];  // A 2x32KB | B 2x24KB

  const int tid = threadIdx.x;
  const int lane = tid & 63;
  const int wid = tid >> 6;
  const int wr = wid >> 2;        // 0..1  (M half: 128 rows)
  const int wc = wid & 3;         // 0..3  (N quarter: 48 cols)

  int mt, nt, zt;
  {
    int bid = blockIdx.x;
    if (MAP == 0) {               // gemm1: XCD owns 8 N-panels, M fastest
      int xcd = bid & 7, r = bid >> 3;
      nt = xcd * 8 + (r >> 3); mt = r & 7; zt = 0;
    } else {                      // gemm2: XCD = K-split
      zt = bid & 7; int r = bid >> 3;
      nt = r & 3; mt = r >> 2;
    }
  }
  const int rm0 = mt * 256;
  const int cn0 = nt * 192;
  const int kbeg = zt * kchunk;

  // ---- affine staging pointers at tile 0 (pre-swizzled source, rule #21) ----
  auto gsrc = [&](const unsigned short* base, int ld, int row0, int j) {
    int off = j * 8192 + tid * 16;
    int row = off >> 7, inrow = off & 127;
    int scol = inrow ^ ((row & 7) << 4);
    return (const char*)base + ((size_t)(row0 + row) * ld + kbeg) * 2 + scol;
  };
  const char* pA0 = gsrc(Ag, lda, rm0, 0);
  const char* pA1 = gsrc(Ag, lda, rm0, 1);
  const char* pA2 = gsrc(Ag, lda, rm0, 2);
  const char* pA3 = gsrc(Ag, lda, rm0, 3);
  const char* pB0 = gsrc(Bg, ldb, cn0, 0);
  const char* pB1 = gsrc(Bg, ldb, cn0, 1);
  const char* pB2 = gsrc(Bg, ldb, cn0, 2);

  // ---- precomputed LDS read base offsets (bytes, buffer 0) ----
  const int lswz = (lane & 7) << 4;
  const int colk0 = (((lane >> 4) & 3) * 16) ^ lswz;
  const int colk1 = (64 + ((lane >> 4) & 3) * 16) ^ lswz;
  const int abase0 = wr * 16384 + (lane & 15) * 128 + colk0;
  const int abase1 = wr * 16384 + (lane & 15) * 128 + colk1;
  const int bb0 = wc * 6144 + (lane & 15) * 128 + colk0;
  const int bb1 = wc * 6144 + (lane & 15) * 128 + colk1;

  f32x4 acc[8][3];
#pragma unroll
  for (int m = 0; m < 8; ++m)
#pragma unroll
    for (int n = 0; n < 3; ++n) acc[m][n] = (f32x4){0.f, 0.f, 0.f, 0.f};

  // prologue: stage tile 0 into buf 0 (same issue order as steady state)
  gload16(pB0, smem + 65536 + wid * 1024);
  gload16(pB1, smem + 65536 + 8192 + wid * 1024);
  gload16(pB2, smem + 65536 + 16384 + wid * 1024);
  gload16(pA0, smem + wid * 1024);
  gload16(pA2, smem + 16384 + wid * 1024);
  gload16(pA1, smem + 8192 + wid * 1024);
  gload16(pA3, smem + 24576 + wid * 1024);
  pA0 += 128; pA1 += 128; pA2 += 128; pA3 += 128;
  pB0 += 128; pB1 += 128; pB2 += 128;
  __builtin_amdgcn_sched_barrier(0);

  int aoff = 0, boff = 0;
  bf16x8 af[4], ag[4], bfr[3], bgr[3];
  for (int t = 0; t < ntiles; ++t) {
    const int adst = aoff ^ 32768;
    const int bdst = boff ^ 24576;

    // ---- phase 0: m0-3 x all n ----
    asm volatile("s_waitcnt vmcnt(2)" ::: "memory");  // B*,A0,A2 of cur landed
    __builtin_amdgcn_s_barrier();
    __builtin_amdgcn_sched_barrier(0);
#pragma unroll
    for (int m = 0; m < 4; ++m) {
      af[m] = *(const bf16x8*)(smem + aoff + abase0 + m * 2048);
      ag[m] = *(const bf16x8*)(smem + aoff + abase1 + m * 2048);
    }
#pragma unroll
    for (int n = 0; n < 3; ++n) {
      bfr[n] = *(const bf16x8*)(smem + 65536 + boff + bb0 + n * 2048);
      bgr[n] = *(const bf16x8*)(smem + 65536 + boff + bb1 + n * 2048);
    }
    // stage tile t+1 (pointers already advanced to t+1)
    gload16(pB0, smem + 65536 + bdst + wid * 1024);
    gload16(pB1, smem + 65536 + bdst + 8192 + wid * 1024);
    gload16(pB2, smem + 65536 + bdst + 16384 + wid * 1024);
    gload16(pA0, smem + adst + wid * 1024);
    gload16(pA2, smem + adst + 16384 + wid * 1024);
    __builtin_amdgcn_sched_barrier(0);
    __builtin_amdgcn_s_setprio(1);
#pragma unroll
    for (int m = 0; m < 4; ++m)
#pragma unroll
      for (int n = 0; n < 3; ++n) {
        acc[m][n] = __builtin_amdgcn_mfma_f32_16x16x32_bf16(af[m], bfr[n], acc[m][n], 0, 0, 0);
        acc[m][n] = __builtin_amdgcn_mfma_f32_16x16x32_bf16(ag[m], bgr[n], acc[m][n], 0, 0, 0);
      }
    __builtin_amdgcn_s_setprio(0);

    // ---- phase 1: m4-7 x all n ----
    asm volatile("s_waitcnt vmcnt(5)" ::: "memory");  // A1,A3 of cur landed
    __builtin_amdgcn_s_barrier();
    __builtin_amdgcn_sched_barrier(0);
#pragma unroll
    for (int m = 0; m < 4; ++m) {
      af[m] = *(const bf16x8*)(smem + aoff + abase0 + 8192 + m * 2048);
      ag[m] = *(const bf16x8*)(smem + aoff + abase1 + 8192 + m * 2048);
    }
    gload16(pA1, smem + adst + 8192 + wid * 1024);
    gload16(pA3, smem + adst + 24576 + wid * 1024);
    __builtin_amdgcn_sched_barrier(0);
    __builtin_amdgcn_s_setprio(1);
#pragma unroll
    for (int m = 0; m < 4; ++m)
#pragma unroll
      for (int n = 0; n < 3; ++n) {
        acc[4 + m][n] = __builtin_amdgcn_mfma_f32_16x16x32_bf16(af[m], bfr[n], acc[4 + m][n], 0, 0, 0);
        acc[4 + m][n] = __builtin_amdgcn_mfma_f32_16x16x32_bf16(ag[m], bgr[n], acc[4 + m][n], 0, 0, 0);
      }
    __builtin_amdgcn_s_setprio(0);

    pA0 += 128; pA1 += 128; pA2 += 128; pA3 += 128;
    pB0 += 128; pB1 += 128; pB2 += 128;
    aoff = adst; boff = bdst;
  }

  asm volatile("s_waitcnt vmcnt(0)" ::: "memory");  // drain tail stages
  __syncthreads();

  // ---- epilogue ----
  const int r0 = (lane >> 4) * 4;
  const int cl = lane & 15;
  if constexpr (EPI == 1) {
    float* Cwf = (float*)smem;   // reuse staging LDS: [256 rows][16 experts]
    {
      int row = tid >> 1, c8 = (tid & 1) * 8;
      const float* s = comb + (size_t)(rm0 + row) * N_EXP + c8;
      *(float4*)&Cwf[row * 16 + c8] = *(const float4*)s;
      *(float4*)&Cwf[row * 16 + c8 + 4] = *(const float4*)(s + 4);
    }
    __syncthreads();
#pragma unroll
    for (int n = 0; n < 3; ++n) {
      int colg = cn0 + wc * 48 + n * 16 + cl;
      int e = (colg < 4096) ? (colg >> 9) : (8 + ((colg - 4096) >> 10));
#pragma unroll
      for (int m = 0; m < 8; ++m) {
        int rl = wr * 128 + m * 16 + r0;
#pragma unroll
        for (int r = 0; r < 4; ++r) {
          float v = gelu_f(acc[m][n][r]) * Cwf[(rl + r) * 16 + e];
          hout[(size_t)(rm0 + rl + r) * W_TOT + colg] = f2bf(v);
        }
      }
    }
  } else {
    float* pz = pout + (size_t)zt * T_TOK * D_EMB;
#pragma unroll
    for (int n = 0; n < 3; ++n) {
      int colg = cn0 + wc * 48 + n * 16 + cl;
#pragma unroll
      for (int m = 0; m < 8; ++m) {
        int rl = wr * 128 + m * 16 + r0;
#pragma unroll
        for (int r = 0; r < 4; ++r)
          pz[(size_t)(rm0 + rl + r) * D_EMB + colg] = acc[m][n][r];
      }
    }
  }
}

__global__ __launch_bounds__(256) void reduce_kernel(
    const float* __restrict__ partial, float* __restrict__ out, int splits) {
  int i = (blockIdx.x * 256 + threadIdx.x) * 4;
  if (i >= T_TOK * D_EMB) return;
  float4 s = *(const float4*)(partial + i);
  for (int sp = 1; sp < splits; ++sp) {
    float4 v = *(const float4*)(partial + (size_t)sp * T_TOK * D_EMB + i);
    s.x += v.x; s.y += v.y; s.z += v.z; s.w += v.w;
  }
  *(float4*)(out + i) = s;
}

// ---------------- launcher ----------------

extern "C" void kernel_launch(void* const* d_in, const int* in_sizes, int n_in,
                              void* d_out, int out_size, void* d_ws, size_t ws_size,
                              hipStream_t stream) {
  const float* x = (const float*)d_in[0];
  const float* router_w = (const float*)d_in[1];
  const float* w1 = (const float*)d_in[2];
  const float* w2 = (const float*)d_in[3];
  float* out = (float*)d_out;

  char* ws = (char*)d_ws;
  size_t off = 0;
  auto alloc = [&](size_t bytes) {
    char* p = ws + off;
    off += (bytes + 255) & ~(size_t)255;
    return p;
  };
  unsigned short* xb  = (unsigned short*)alloc((size_t)T_TOK * D_EMB * 2);
  unsigned short* w1t = (unsigned short*)alloc((size_t)W_TOT * D_EMB * 2);
  unsigned short* w2t = (unsigned short*)alloc((size_t)D_EMB * W_TOT * 2);
  unsigned short* h   = (unsigned short*)alloc((size_t)T_TOK * W_TOT * 2);
  float* comb         = (float*)alloc((size_t)T_TOK * N_EXP * 4);

  const int splits = 8;                     // grid 256; kchunk 1536 (24 tiles)
  float* partial = (float*)alloc((size_t)splits * T_TOK * D_EMB * 4);
  int kchunk = W_TOT / splits;

  transpose_cvt_kernel<<<dim3(W_TOT / 32, D_EMB / 32), 256, 0, stream>>>(w1, w1t, D_EMB, W_TOT);
  transpose_cvt_kernel<<<dim3(D_EMB / 32, W_TOT / 32), 256, 0, stream>>>(w2, w2t, W_TOT, D_EMB);
  router_kernel<<<T_TOK / 4, 256, 0, stream>>>(x, router_w, comb, xb);

  // GEMM1: H = gelu(X W1) * comb ; grid 512 = 8 XCD x (8 N x 8 M)
  gemm_kernel<1, 0><<<512, 512, 0, stream>>>(
      xb, w1t, D_EMB, D_EMB, D_EMB / 64, D_EMB, comb, h, nullptr);

  // GEMM2: OUT = H W2 ; grid 256 = 8 splits x (4 N x 8 M)
  gemm_kernel<0, 1><<<256, 512, 0, stream>>>(
      h, w2t, W_TOT, W_TOT, kchunk / 64, kchunk, nullptr, nullptr, partial);

  reduce_kernel<<<(T_TOK * D_EMB) / 1024, 256, 0, stream>>>(partial, out, splits);
}